// Round 7
// baseline (10292.905 us; speedup 1.0000x reference)
//
#include <hip/hip_runtime.h>
#include <hip/hip_cooperative_groups.h>
#include <math.h>

namespace cg = cooperative_groups;

#define BB 4
#define TT 32
#define NN 1024
#define KK 16
#define HDIM 128
#define NO 512            // 4*HD gate rows
#define KG 132            // 4+HD contraction

// d_out offsets (floats)
#define OUT1_SZ ((size_t)BB*TT*132*NN)
#define OH (OUT1_SZ)
#define OC (OH + (size_t)BB*HDIM*NN)
#define OG (OC + (size_t)BB*HDIM*NN)

// ---------------------------------------------------------------------------
// Weight prep: transposed effective weights [k][512].
// ---------------------------------------------------------------------------
__global__ __launch_bounds__(256) void prep_weights(
    const float* __restrict__ w0, const float* __restrict__ w1,
    float* __restrict__ WaT0, float* __restrict__ WgT0,
    float* __restrict__ WaT1, float* __restrict__ WgT1)
{
  int idx = blockIdx.x * 256 + threadIdx.x;
  if (idx >= KG * NO) return;
  int k = idx / NO, o = idx - k * NO;
  WgT0[idx] = w0[o * 136 + 4 + k];
  WgT1[idx] = w1[o * 264 + 132 + k];
  float a1 = w1[o * 264 + k];
  if (k < 4) a1 -= w1[o * 264 + 132 + k];
  WaT1[idx] = a1;
  if (k < 4) WaT0[k * NO + o] = w0[o * 136 + k] - w0[o * 136 + 4 + k];
}

// ---------------------------------------------------------------------------
// KNN — VERBATIM the proven R1 kernel. Do not modify.
// ---------------------------------------------------------------------------
__global__ __launch_bounds__(512) void knn_kernel(
    const float* __restrict__ x, int* __restrict__ gind, float* __restrict__ gfloat)
{
  __shared__ float rx[NN], ry[NN], rz[NN], rr[NN];
  int b = blockIdx.z, t = blockIdx.y;
  int tp = (t == 0) ? 0 : t - 1;
  const float* xr = x + (size_t)(b * TT + tp) * 4 * NN;
  for (int m = threadIdx.x; m < NN; m += 512) {
    float a = xr[m], e = xr[NN + m], c = xr[2 * NN + m];
    rx[m] = a; ry[m] = e; rz[m] = c;
    rr[m] = __fadd_rn(__fadd_rn(__fmul_rn(a, a), __fmul_rn(e, e)), __fmul_rn(c, c));
  }
  __syncthreads();
  int n = blockIdx.x * 512 + threadIdx.x;
  const float* xq = x + (size_t)(b * TT + t) * 4 * NN;
  float qx = xq[n], qy = xq[NN + n], qz = xq[2 * NN + n];
  float q2 = __fadd_rn(__fadd_rn(__fmul_rn(qx, qx), __fmul_rn(qy, qy)), __fmul_rn(qz, qz));
  float bd[KK]; int bi[KK];
#pragma unroll
  for (int i = 0; i < KK; ++i) { bd[i] = 3.402823466e38f; bi[i] = 0; }
  for (int m = 0; m < NN; ++m) {
    float s = __fmaf_rn(qz, rz[m], __fmaf_rn(qy, ry[m], __fmaf_rn(qx, rx[m], 0.0f)));
    float d2 = __fsub_rn(__fadd_rn(q2, rr[m]), __fmul_rn(2.0f, s));
    if (d2 < bd[KK - 1]) {
#pragma unroll
      for (int i = KK - 1; i > 0; --i) {
        float pv = bd[i - 1]; int pi = bi[i - 1];
        if (pv > d2)            { bd[i] = pv; bi[i] = pi; }
        else if (bd[i] > d2)    { bd[i] = d2; bi[i] = m; }
      }
      if (bd[0] > d2) { bd[0] = d2; bi[0] = m; }
    }
  }
  size_t base = ((size_t)(b * TT + t) * NN + n) * KK;
#pragma unroll
  for (int i = 0; i < KK; ++i) { gind[base + i] = bi[i]; gfloat[base + i] = (float)bi[i]; }
}

// ---------------------------------------------------------------------------
// Persistent cooperative t-loop. 256 blocks x 1024 threads (1/CU).
// Phases per t (grid.sync between):
//   G : G0=Wg0@[pp;h0_{t-1}], G1=Wg1@[pp;h1_{t-1}], A0=Wa0@pos+b0  (o-partitioned)
//   E0: layer-0 ew (proven body) -> h0T, c0
//   A1: A1=Wa1@[pos;h0_t]+b1                                        (o-partitioned)
//   E1: layer-1 ew -> out slot t, c1
// ---------------------------------------------------------------------------
struct LoopParams {
  const float* x;
  const int*   gind;
  const float* WaT0; const float* WgT0; const float* WaT1; const float* WgT1;
  const float* b0;   const float* b1;
  float* h0T; const float* zeros;
  float* c0a; float* c0b; float* c1a; float* c1b;
  float* A0;  float* G0;  float* A1;  float* G1;
  float* out;
};

__device__ __forceinline__ void ew_phase(
    int bid, int nblk, int tid,
    const float* __restrict__ A, const float* __restrict__ G,
    const int* __restrict__ gind,
    const float* __restrict__ c_in, float* __restrict__ c_out,
    float* __restrict__ hT, size_t hT_bstr, int t,
    float (*htile)[9])
{
  int j = tid & 127, ns = tid >> 7;
  for (int u = bid; u < 512; u += nblk) {
    int b = u >> 7, nb8 = u & 127;
    int n = nb8 * 8 + ns;
    const float* Ap = A + ((size_t)b * NN + n) * NO;
    float a0 = Ap[j], a1 = Ap[128 + j], a2 = Ap[256 + j], a3 = Ap[384 + j];
    const int* ip = gind + ((size_t)(b * TT + t) * NN + n) * KK;
    const float* Gb = G + (size_t)b * NN * NO;
    const float* cb = c_in + (size_t)b * NN * HDIM;
    float hmax = -3.402823466e38f, cmax = -3.402823466e38f;
#pragma unroll 4
    for (int k = 0; k < KK; ++k) {
      int m = __builtin_amdgcn_readfirstlane(ip[k]);   // wave-uniform
      const float* Gp = Gb + (size_t)m * NO;
      float gi = a0 + Gp[j];
      float gf = a1 + Gp[128 + j];
      float go = a2 + Gp[256 + j];
      float gg = a3 + Gp[384 + j];
      float cg = cb[(size_t)m * HDIM + j];
      float si = 1.0f / (1.0f + __expf(-gi));
      float sf = 1.0f / (1.0f + __expf(-gf));
      float so = 1.0f / (1.0f + __expf(-go));
      float tg = 1.0f - 2.0f / (1.0f + __expf(2.0f * gg));
      float cn = sf * cg + si * tg;
      float tc = 1.0f - 2.0f / (1.0f + __expf(2.0f * cn));
      float hn = so * tc;
      hmax = fmaxf(hmax, hn);
      cmax = fmaxf(cmax, cn);
    }
    c_out[((size_t)b * NN + n) * HDIM + j] = cmax;
    htile[j][ns] = hmax;
    __syncthreads();
    int jw = tid >> 3, nn = tid & 7;
    hT[(size_t)b * hT_bstr + (size_t)jw * NN + nb8 * 8 + nn] = htile[jw][nn];
    __syncthreads();
  }
}

__global__ __launch_bounds__(1024, 4) void lstm_loop(LoopParams p)
{
  cg::grid_group grid = cg::this_grid();
  const int bid = blockIdx.x;
  const int nblk = gridDim.x;
  const int tid = threadIdx.x;
  __shared__ float htile[HDIM][9];

  const size_t H_BSTR = (size_t)HDIM * NN;
  const size_t OUT_BSTR = (size_t)TT * 132 * NN;
  const int w = tid >> 6, lane = tid & 63;

  for (int t = 0; t < TT; ++t) {
    int tp = t ? t - 1 : 0;
    const float* h0prev = t ? p.h0T : p.zeros;
    size_t h0bs = t ? H_BSTR : 0;
    const float* h1prev = t ? (p.out + ((size_t)(t - 1) * 132 + 4) * NN) : p.zeros;
    size_t h1bs = t ? OUT_BSTR : 0;
    const float* c0in = (t & 1) ? p.c0b : p.c0a;
    float*       c0out = (t & 1) ? p.c0a : p.c0b;
    const float* c1in = (t & 1) ? p.c1b : p.c1a;
    float*       c1out = (t & 1) ? p.c1a : p.c1b;

    // ================= phase G: G0, G1, A0 =================
    for (int u = bid; u < 512; u += nblk) {
      int b = u >> 7, rest = u & 127, nb = rest >> 3, ob = rest & 7;
      int o0u = __builtin_amdgcn_readfirstlane(ob * 64 + w * 4);
      int n = nb * 64 + lane;
      float aG0[4] = {0.f, 0.f, 0.f, 0.f};
      float aG1[4] = {0.f, 0.f, 0.f, 0.f};
      float aA0[4] = {0.f, 0.f, 0.f, 0.f};
      const float* xg = p.x + (size_t)(b * TT + tp) * 4 * NN + n;
      const float* xa = p.x + (size_t)(b * TT + t) * 4 * NN + n;
#pragma unroll
      for (int k = 0; k < 4; ++k) {
        const float* wg0 = p.WgT0 + (size_t)k * NO + o0u;
        const float* wg1 = p.WgT1 + (size_t)k * NO + o0u;
        const float* wa0 = p.WaT0 + (size_t)k * NO + o0u;
        float gv = xg[(size_t)k * NN];
        float av = xa[(size_t)k * NN];
#pragma unroll
        for (int i = 0; i < 4; ++i) {
          aG0[i] = fmaf(wg0[i], gv, aG0[i]);
          aG1[i] = fmaf(wg1[i], gv, aG1[i]);
          aA0[i] = fmaf(wa0[i], av, aA0[i]);
        }
      }
      const float* h0 = h0prev + (size_t)b * h0bs + n;
      const float* h1 = h1prev + (size_t)b * h1bs + n;
#pragma unroll 4
      for (int k = 0; k < HDIM; ++k) {
        const float* wg0 = p.WgT0 + (size_t)(4 + k) * NO + o0u;
        const float* wg1 = p.WgT1 + (size_t)(4 + k) * NO + o0u;
        float g0 = h0[(size_t)k * NN];
        float g1 = h1[(size_t)k * NN];
#pragma unroll
        for (int i = 0; i < 4; ++i) {
          aG0[i] = fmaf(wg0[i], g0, aG0[i]);
          aG1[i] = fmaf(wg1[i], g1, aG1[i]);
        }
      }
      const float* bv = p.b0 + o0u;
      size_t row = ((size_t)b * NN + n) * NO + o0u;
      *(float4*)&p.G0[row] = make_float4(aG0[0], aG0[1], aG0[2], aG0[3]);
      *(float4*)&p.G1[row] = make_float4(aG1[0], aG1[1], aG1[2], aG1[3]);
      *(float4*)&p.A0[row] = make_float4(aA0[0] + bv[0], aA0[1] + bv[1],
                                         aA0[2] + bv[2], aA0[3] + bv[3]);
    }
    grid.sync();

    // ================= phase E0: layer-0 ew =================
    ew_phase(bid, nblk, tid, p.A0, p.G0, p.gind, c0in, c0out,
             p.h0T, H_BSTR, t, htile);
    grid.sync();

    // ================= phase A1: A1 = Wa1@[pos; h0_t] + b1 =================
    for (int u = bid; u < 512; u += nblk) {
      int b = u >> 7, rest = u & 127, nb = rest >> 3, ob = rest & 7;
      int o0u = __builtin_amdgcn_readfirstlane(ob * 64 + w * 4);
      int n = nb * 64 + lane;
      float aA[4] = {0.f, 0.f, 0.f, 0.f};
      const float* xa = p.x + (size_t)(b * TT + t) * 4 * NN + n;
#pragma unroll
      for (int k = 0; k < 4; ++k) {
        const float* wa = p.WaT1 + (size_t)k * NO + o0u;
        float av = xa[(size_t)k * NN];
#pragma unroll
        for (int i = 0; i < 4; ++i) aA[i] = fmaf(wa[i], av, aA[i]);
      }
      const float* ha = p.h0T + (size_t)b * H_BSTR + n;
#pragma unroll 4
      for (int k = 0; k < HDIM; ++k) {
        const float* wa = p.WaT1 + (size_t)(4 + k) * NO + o0u;
        float av = ha[(size_t)k * NN];
#pragma unroll
        for (int i = 0; i < 4; ++i) aA[i] = fmaf(wa[i], av, aA[i]);
      }
      const float* bv = p.b1 + o0u;
      size_t row = ((size_t)b * NN + n) * NO + o0u;
      *(float4*)&p.A1[row] = make_float4(aA[0] + bv[0], aA[1] + bv[1],
                                         aA[2] + bv[2], aA[3] + bv[3]);
    }
    grid.sync();

    // ================= phase E1: layer-1 ew -> out slot t =================
    ew_phase(bid, nblk, tid, p.A1, p.G1, p.gind, c1in, c1out,
             p.out + ((size_t)t * 132 + 4) * NN, OUT_BSTR, t, htile);
    grid.sync();
  }
}

// Transpose (b,n,j)[N][128] -> dst[dstBase + b*bStride + j*N + n]  (for c out)
__global__ __launch_bounds__(256) void transpose_nj_jn(
    const float* __restrict__ src, float* __restrict__ dst,
    size_t dstBase, size_t bStride)
{
  __shared__ float tl[64][65];
  int tid = threadIdx.x;
  int n0 = blockIdx.x * 64, j0 = blockIdx.y * 64, b = blockIdx.z;
  int c = tid & 63, r4 = tid >> 6;
#pragma unroll
  for (int i = 0; i < 16; ++i) {
    int r = r4 + i * 4;
    tl[r][c] = src[((size_t)b * NN + n0 + r) * HDIM + j0 + c];
  }
  __syncthreads();
  float* dp = dst + dstBase + (size_t)b * bStride;
#pragma unroll
  for (int i = 0; i < 16; ++i) {
    int rr = r4 + i * 4;
    dp[(size_t)(j0 + rr) * NN + n0 + c] = tl[c][rr];
  }
}

// h output = copy of out1 slot at t=T-1 (already j-major)
__global__ __launch_bounds__(256) void copy_h(const float* __restrict__ out1,
                                              float* __restrict__ dst)
{
  int i = blockIdx.x * 256 + threadIdx.x;
  if (i >= BB * HDIM * NN) return;
  int b = i / (HDIM * NN);
  int r = i - b * (HDIM * NN);
  dst[i] = out1[((size_t)(b * TT + TT - 1) * 132 + 4) * NN + r];
}

// out1 position channels
__global__ __launch_bounds__(256) void pos_copy(const float* __restrict__ x,
                                                float* __restrict__ out)
{
  int i = blockIdx.x * 256 + threadIdx.x;
  if (i >= BB * TT * 4 * NN) return;
  int n = i & (NN - 1);
  int btc = i >> 10;
  int c = btc & 3, bt = btc >> 2;
  out[((size_t)bt * 132 + c) * NN + n] = x[i];
}

extern "C" void kernel_launch(void* const* d_in, const int* in_sizes, int n_in,
                              void* d_out, int out_size, void* d_ws, size_t ws_size,
                              hipStream_t stream)
{
  const float* x  = (const float*)d_in[0];
  const float* w0 = (const float*)d_in[1];
  const float* b0 = (const float*)d_in[2];
  const float* w1 = (const float*)d_in[3];
  const float* b1 = (const float*)d_in[4];
  float* out = (float*)d_out;

  float* wsf = (float*)d_ws;
  int*   gind = (int*)d_ws;
  size_t off = (size_t)BB * TT * NN * KK;          // gind ints
  const size_t HSZ = (size_t)BB * NN * HDIM;       // 524288
  float* h0T = wsf + off; off += HSZ;
  float* c0a = wsf + off; off += HSZ;
  float* c0b = wsf + off; off += HSZ;
  float* c1a = wsf + off; off += HSZ;
  float* c1b = wsf + off; off += HSZ;
  float* zeros = wsf + off; off += (size_t)HDIM * NN;
  float* A0buf = wsf + off; off += (size_t)BB * NN * NO;
  float* G0buf = wsf + off; off += (size_t)BB * NN * NO;
  float* A1buf = wsf + off; off += (size_t)BB * NN * NO;
  float* G1buf = wsf + off; off += (size_t)BB * NN * NO;
  float* WaT0 = wsf + off; off += 4 * NO;
  float* WgT0 = wsf + off; off += (size_t)KG * NO;
  float* WaT1 = wsf + off; off += (size_t)KG * NO;
  float* WgT1 = wsf + off; off += (size_t)KG * NO;

  hipMemsetAsync(c0a, 0, HSZ * 4, stream);
  hipMemsetAsync(c1a, 0, HSZ * 4, stream);
  hipMemsetAsync(zeros, 0, (size_t)HDIM * NN * 4, stream);

  prep_weights<<<(KG * NO + 255) / 256, 256, 0, stream>>>(w0, w1, WaT0, WgT0, WaT1, WgT1);
  knn_kernel<<<dim3(2, TT, BB), 512, 0, stream>>>(x, gind, out + OG);
  pos_copy<<<(BB * TT * 4 * NN + 255) / 256, 256, 0, stream>>>(x, out);

  LoopParams P;
  P.x = x; P.gind = gind;
  P.WaT0 = WaT0; P.WgT0 = WgT0; P.WaT1 = WaT1; P.WgT1 = WgT1;
  P.b0 = b0; P.b1 = b1;
  P.h0T = h0T; P.zeros = zeros;
  P.c0a = c0a; P.c0b = c0b; P.c1a = c1a; P.c1b = c1b;
  P.A0 = A0buf; P.G0 = G0buf; P.A1 = A1buf; P.G1 = G1buf;
  P.out = out;
  void* args[] = { &P };
  hipLaunchCooperativeKernel((void*)lstm_loop, dim3(256), dim3(1024), args, 0, stream);

  // final h (copy of last out1 slot) and c (transpose; t=31 writes c1 into c1a)
  copy_h<<<(BB * HDIM * NN + 255) / 256, 256, 0, stream>>>(out, out + OH);
  transpose_nj_jn<<<dim3(16, 2, BB), 256, 0, stream>>>(c1a, out, OC, (size_t)HDIM * NN);
}

// Round 8
// 3844.600 us; speedup vs baseline: 2.6772x; 2.6772x over previous
//
#include <hip/hip_runtime.h>
#include <math.h>

#define BB 4
#define TT 32
#define NN 1024
#define KK 16
#define HDIM 128
#define NO 512            // 4*HD gate rows
#define KG 132            // 4+HD contraction

// d_out offsets (floats)
#define OUT1_SZ ((size_t)BB*TT*132*NN)
#define OH (OUT1_SZ)
#define OC (OH + (size_t)BB*HDIM*NN)
#define OG (OC + (size_t)BB*HDIM*NN)

// ---------------------------------------------------------------------------
// Weight prep: transposed effective weights [k][512].
// ---------------------------------------------------------------------------
__global__ __launch_bounds__(256) void prep_weights(
    const float* __restrict__ w0, const float* __restrict__ w1,
    float* __restrict__ WaT0, float* __restrict__ WgT0,
    float* __restrict__ WaT1, float* __restrict__ WgT1)
{
  int idx = blockIdx.x * 256 + threadIdx.x;
  if (idx >= KG * NO) return;
  int k = idx / NO, o = idx - k * NO;
  WgT0[idx] = w0[o * 136 + 4 + k];
  WgT1[idx] = w1[o * 264 + 132 + k];
  float a1 = w1[o * 264 + k];
  if (k < 4) a1 -= w1[o * 264 + 132 + k];
  WaT1[idx] = a1;
  if (k < 4) WaT0[k * NO + o] = w0[o * 136 + k] - w0[o * 136 + 4 + k];
}

// ---------------------------------------------------------------------------
// KNN — VERBATIM the proven R1 kernel. Do not modify (two rewrites failed
// group_ind identically; mechanism unexplained — frozen).
// ---------------------------------------------------------------------------
__global__ __launch_bounds__(512) void knn_kernel(
    const float* __restrict__ x, int* __restrict__ gind, float* __restrict__ gfloat)
{
  __shared__ float rx[NN], ry[NN], rz[NN], rr[NN];
  int b = blockIdx.z, t = blockIdx.y;
  int tp = (t == 0) ? 0 : t - 1;
  const float* xr = x + (size_t)(b * TT + tp) * 4 * NN;
  for (int m = threadIdx.x; m < NN; m += 512) {
    float a = xr[m], e = xr[NN + m], c = xr[2 * NN + m];
    rx[m] = a; ry[m] = e; rz[m] = c;
    rr[m] = __fadd_rn(__fadd_rn(__fmul_rn(a, a), __fmul_rn(e, e)), __fmul_rn(c, c));
  }
  __syncthreads();
  int n = blockIdx.x * 512 + threadIdx.x;
  const float* xq = x + (size_t)(b * TT + t) * 4 * NN;
  float qx = xq[n], qy = xq[NN + n], qz = xq[2 * NN + n];
  float q2 = __fadd_rn(__fadd_rn(__fmul_rn(qx, qx), __fmul_rn(qy, qy)), __fmul_rn(qz, qz));
  float bd[KK]; int bi[KK];
#pragma unroll
  for (int i = 0; i < KK; ++i) { bd[i] = 3.402823466e38f; bi[i] = 0; }
  for (int m = 0; m < NN; ++m) {
    float s = __fmaf_rn(qz, rz[m], __fmaf_rn(qy, ry[m], __fmaf_rn(qx, rx[m], 0.0f)));
    float d2 = __fsub_rn(__fadd_rn(q2, rr[m]), __fmul_rn(2.0f, s));
    if (d2 < bd[KK - 1]) {
#pragma unroll
      for (int i = KK - 1; i > 0; --i) {
        float pv = bd[i - 1]; int pi = bi[i - 1];
        if (pv > d2)            { bd[i] = pv; bi[i] = pi; }
        else if (bd[i] > d2)    { bd[i] = d2; bi[i] = m; }
      }
      if (bd[0] > d2) { bd[0] = d2; bi[0] = m; }
    }
  }
  size_t base = ((size_t)(b * TT + t) * NN + n) * KK;
#pragma unroll
  for (int i = 0; i < KK; ++i) { gind[base + i] = bi[i]; gfloat[base + i] = (float)bi[i]; }
}

// ---------------------------------------------------------------------------
// GEMM (R5-proven body). 1D grid 2048; XCD-locality swizzle: batch b lands on
// XCD pair {2b,2b+1} (bid%8 -> XCD round-robin), so G/A slabs for b stay in
// that pair's L2 for the following ew gather.
// ---------------------------------------------------------------------------
template<int KA>
__global__ __launch_bounds__(256) void gemm_ag(
    const float* __restrict__ WgT, const float* __restrict__ WaT,
    const float* __restrict__ bias, const float* __restrict__ x,
    const float* __restrict__ hTg, size_t hTg_bstr,
    const float* __restrict__ hTa,
    int t, int tp,
    float* __restrict__ Aout, float* __restrict__ Gout)
{
  int tid = threadIdx.x;
  int w = tid >> 6, lane = tid & 63;
  int bid = blockIdx.x;
  int b = (bid >> 1) & 3;
  int sub = (bid >> 3) * 2 + (bid & 1);       // [0,512) bijective per b
  int ob = sub >> 4, nb = sub & 15;
  int o0u = __builtin_amdgcn_readfirstlane(ob * 16 + w * 4);
  int n = nb * 64 + lane;

  float aG[4] = {0.f, 0.f, 0.f, 0.f};
  float aA[4] = {0.f, 0.f, 0.f, 0.f};

  const float* xg = x + (size_t)(b * TT + tp) * 4 * NN + n;  // pp frame
  const float* xa = x + (size_t)(b * TT + t) * 4 * NN + n;   // cur frame

#pragma unroll
  for (int k = 0; k < 4; ++k) {
    const float* wg = WgT + (size_t)k * NO + o0u;
    const float* wa = WaT + (size_t)k * NO + o0u;
    float gv = xg[(size_t)k * NN];
    float av = xa[(size_t)k * NN];
#pragma unroll
    for (int i = 0; i < 4; ++i) {
      aG[i] = fmaf(wg[i], gv, aG[i]);
      aA[i] = fmaf(wa[i], av, aA[i]);
    }
  }

  const float* hg = hTg + (size_t)b * hTg_bstr + n;
  const float* ha = hTa + (size_t)b * (HDIM * NN) + n;
#pragma unroll 4
  for (int k = 0; k < HDIM; ++k) {
    const float* wg = WgT + (size_t)(4 + k) * NO + o0u;
    float gv = hg[(size_t)k * NN];
#pragma unroll
    for (int i = 0; i < 4; ++i) aG[i] = fmaf(wg[i], gv, aG[i]);
    if (KA == 132) {
      const float* wa = WaT + (size_t)(4 + k) * NO + o0u;
      float av = ha[(size_t)k * NN];
#pragma unroll
      for (int i = 0; i < 4; ++i) aA[i] = fmaf(wa[i], av, aA[i]);
    }
  }

  const float* bv = bias + o0u;
  size_t row = ((size_t)b * NN + n) * NO + o0u;
  *(float4*)&Gout[row] = make_float4(aG[0], aG[1], aG[2], aG[3]);
  *(float4*)&Aout[row] = make_float4(aA[0] + bv[0], aA[1] + bv[1],
                                     aA[2] + bv[2], aA[3] + bv[3]);
}

// ---------------------------------------------------------------------------
// Elementwise LSTM step (R5-proven body). 1D grid 512 with the same b->XCD
// pair swizzle so gathers hit the L2 lines the gemm just wrote.
// ---------------------------------------------------------------------------
__global__ __launch_bounds__(1024) void ew_step(
    const float* __restrict__ A, const float* __restrict__ G,
    const int* __restrict__ gind,
    const float* __restrict__ c_in, float* __restrict__ c_out,
    float* __restrict__ hT, size_t hT_bstr, int t)
{
  __shared__ float htile[HDIM][9];
  int tid = threadIdx.x;
  int j = tid & 127, ns = tid >> 7;     // ns 0..7
  int bid = blockIdx.x;
  int b = (bid >> 1) & 3;
  int nb8 = (bid >> 3) * 2 + (bid & 1);       // [0,128)
  int n = nb8 * 8 + ns;
  const float* Ap = A + ((size_t)b * NN + n) * NO;
  float a0 = Ap[j], a1 = Ap[128 + j], a2 = Ap[256 + j], a3 = Ap[384 + j];
  const int* ip = gind + ((size_t)(b * TT + t) * NN + n) * KK;
  const float* Gb = G + (size_t)b * NN * NO;
  const float* cb = c_in + (size_t)b * NN * HDIM;
  float hmax = -3.402823466e38f, cmax = -3.402823466e38f;
#pragma unroll 4
  for (int k = 0; k < KK; ++k) {
    int m = __builtin_amdgcn_readfirstlane(ip[k]);   // wave-uniform
    const float* Gp = Gb + (size_t)m * NO;
    float gi = a0 + Gp[j];
    float gf = a1 + Gp[128 + j];
    float go = a2 + Gp[256 + j];
    float gg = a3 + Gp[384 + j];
    float cg = cb[(size_t)m * HDIM + j];
    float si = 1.0f / (1.0f + __expf(-gi));
    float sf = 1.0f / (1.0f + __expf(-gf));
    float so = 1.0f / (1.0f + __expf(-go));
    float tg = 1.0f - 2.0f / (1.0f + __expf(2.0f * gg));
    float cn = sf * cg + si * tg;
    float tc = 1.0f - 2.0f / (1.0f + __expf(2.0f * cn));
    float hn = so * tc;
    hmax = fmaxf(hmax, hn);
    cmax = fmaxf(cmax, cn);
  }
  c_out[((size_t)b * NN + n) * HDIM + j] = cmax;
  htile[j][ns] = hmax;
  __syncthreads();
  int jw = tid >> 3, nn = tid & 7;
  hT[(size_t)b * hT_bstr + (size_t)jw * NN + nb8 * 8 + nn] = htile[jw][nn];
}

// Transpose (b,n,j)[N][128] -> dst[dstBase + b*bStride + j*N + n]  (for c out)
__global__ __launch_bounds__(256) void transpose_nj_jn(
    const float* __restrict__ src, float* __restrict__ dst,
    size_t dstBase, size_t bStride)
{
  __shared__ float tl[64][65];
  int tid = threadIdx.x;
  int n0 = blockIdx.x * 64, j0 = blockIdx.y * 64, b = blockIdx.z;
  int c = tid & 63, r4 = tid >> 6;
#pragma unroll
  for (int i = 0; i < 16; ++i) {
    int r = r4 + i * 4;
    tl[r][c] = src[((size_t)b * NN + n0 + r) * HDIM + j0 + c];
  }
  __syncthreads();
  float* dp = dst + dstBase + (size_t)b * bStride;
#pragma unroll
  for (int i = 0; i < 16; ++i) {
    int rr = r4 + i * 4;
    dp[(size_t)(j0 + rr) * NN + n0 + c] = tl[c][rr];
  }
}

// h output = copy of out1 slot at t=T-1 (already j-major)
__global__ __launch_bounds__(256) void copy_h(const float* __restrict__ out1,
                                              float* __restrict__ dst)
{
  int i = blockIdx.x * 256 + threadIdx.x;
  if (i >= BB * HDIM * NN) return;
  int b = i / (HDIM * NN);
  int r = i - b * (HDIM * NN);
  dst[i] = out1[((size_t)(b * TT + TT - 1) * 132 + 4) * NN + r];
}

// out1 position channels
__global__ __launch_bounds__(256) void pos_copy(const float* __restrict__ x,
                                                float* __restrict__ out)
{
  int i = blockIdx.x * 256 + threadIdx.x;
  if (i >= BB * TT * 4 * NN) return;
  int n = i & (NN - 1);
  int btc = i >> 10;
  int c = btc & 3, bt = btc >> 2;
  out[((size_t)bt * 132 + c) * NN + n] = x[i];
}

extern "C" void kernel_launch(void* const* d_in, const int* in_sizes, int n_in,
                              void* d_out, int out_size, void* d_ws, size_t ws_size,
                              hipStream_t stream)
{
  const float* x  = (const float*)d_in[0];
  const float* w0 = (const float*)d_in[1];
  const float* b0 = (const float*)d_in[2];
  const float* w1 = (const float*)d_in[3];
  const float* b1 = (const float*)d_in[4];
  float* out = (float*)d_out;

  float* wsf = (float*)d_ws;
  int*   gind = (int*)d_ws;
  size_t off = (size_t)BB * TT * NN * KK;          // gind ints
  const size_t HSZ = (size_t)BB * NN * HDIM;       // 524288
  float* h0T = wsf + off; off += HSZ;
  float* c0a = wsf + off; off += HSZ;
  float* c0b = wsf + off; off += HSZ;
  float* c1a = wsf + off; off += HSZ;
  float* c1b = wsf + off; off += HSZ;
  float* zeros = wsf + off; off += (size_t)HDIM * NN;
  float* Abuf = wsf + off; off += (size_t)BB * NN * NO;
  float* Gbuf = wsf + off; off += (size_t)BB * NN * NO;
  float* WaT0 = wsf + off; off += 4 * NO;
  float* WgT0 = wsf + off; off += (size_t)KG * NO;
  float* WaT1 = wsf + off; off += (size_t)KG * NO;
  float* WgT1 = wsf + off; off += (size_t)KG * NO;

  hipMemsetAsync(c0a, 0, HSZ * 4, stream);
  hipMemsetAsync(c1a, 0, HSZ * 4, stream);
  hipMemsetAsync(zeros, 0, (size_t)HDIM * NN * 4, stream);

  prep_weights<<<(KG * NO + 255) / 256, 256, 0, stream>>>(w0, w1, WaT0, WgT0, WaT1, WgT1);
  knn_kernel<<<dim3(2, TT, BB), 512, 0, stream>>>(x, gind, out + OG);
  pos_copy<<<(BB * TT * 4 * NN + 255) / 256, 256, 0, stream>>>(x, out);

  const size_t H_BSTR = (size_t)HDIM * NN;
  const size_t OUT_BSTR = (size_t)TT * 132 * NN;

  float* c0[2] = {c0a, c0b};
  float* c1[2] = {c1a, c1b};
  for (int t = 0; t < TT; ++t) {
    int tp = t ? t - 1 : 0;
    // ---- layer 0: G = Wg0@[pp; h0_{t-1}], A = Wa0@pos + b0
    const float* hTg0 = t ? h0T : zeros;
    gemm_ag<4><<<dim3(2048), 256, 0, stream>>>(
        WgT0, WaT0, b0, x, hTg0, t ? H_BSTR : 0, h0T, t, tp, Abuf, Gbuf);
    ew_step<<<dim3(512), 1024, 0, stream>>>(
        Abuf, Gbuf, gind, c0[t & 1], c0[(t & 1) ^ 1], h0T, H_BSTR, t);
    // ---- layer 1: G = Wg1@[pp; h1_{t-1}], A = Wa1@[pos; h0_t] + b1
    const float* hTg1 = t ? (out + ((size_t)(t - 1) * 132 + 4) * NN) : zeros;
    gemm_ag<132><<<dim3(2048), 256, 0, stream>>>(
        WgT1, WaT1, b1, x, hTg1, t ? OUT_BSTR : 0, h0T, t, tp, Abuf, Gbuf);
    ew_step<<<dim3(512), 1024, 0, stream>>>(
        Abuf, Gbuf, gind, c1[t & 1], c1[(t & 1) ^ 1],
        out + ((size_t)t * 132 + 4) * NN, OUT_BSTR, t);
  }
  // final h (copy of last out1 slot) and c (transpose)
  copy_h<<<(BB * HDIM * NN + 255) / 256, 256, 0, stream>>>(out, out + OH);
  transpose_nj_jn<<<dim3(16, 2, BB), 256, 0, stream>>>(c1[0], out, OC, (size_t)HDIM * NN);
}

// Round 10
// 3741.264 us; speedup vs baseline: 2.7512x; 1.0276x over previous
//
#include <hip/hip_runtime.h>
#include <math.h>

#define BB 4
#define TT 32
#define NN 1024
#define KK 16
#define HDIM 128
#define NO 512            // 4*HD gate rows
#define KG 132            // 4+HD contraction

// d_out offsets (floats)
#define OUT1_SZ ((size_t)BB*TT*132*NN)
#define OH (OUT1_SZ)
#define OC (OH + (size_t)BB*HDIM*NN)
#define OG (OC + (size_t)BB*HDIM*NN)

#define H_BSTR ((size_t)HDIM * NN)
#define OUT_BSTR ((size_t)TT * 132 * NN)

// ---------------------------------------------------------------------------
// Weight prep: transposed effective weights [k][512].
// ---------------------------------------------------------------------------
__global__ __launch_bounds__(256) void prep_weights(
    const float* __restrict__ w0, const float* __restrict__ w1,
    float* __restrict__ WaT0, float* __restrict__ WgT0,
    float* __restrict__ WaT1, float* __restrict__ WgT1)
{
  int idx = blockIdx.x * 256 + threadIdx.x;
  if (idx >= KG * NO) return;
  int k = idx / NO, o = idx - k * NO;
  WgT0[idx] = w0[o * 136 + 4 + k];
  WgT1[idx] = w1[o * 264 + 132 + k];
  float a1 = w1[o * 264 + k];
  if (k < 4) a1 -= w1[o * 264 + 132 + k];
  WaT1[idx] = a1;
  if (k < 4) WaT0[k * NO + o] = w0[o * 136 + k] - w0[o * 136 + 4 + k];
}

// ---------------------------------------------------------------------------
// KNN — VERBATIM the proven R1 kernel. FROZEN.
// ---------------------------------------------------------------------------
__global__ __launch_bounds__(512) void knn_kernel(
    const float* __restrict__ x, int* __restrict__ gind, float* __restrict__ gfloat)
{
  __shared__ float rx[NN], ry[NN], rz[NN], rr[NN];
  int b = blockIdx.z, t = blockIdx.y;
  int tp = (t == 0) ? 0 : t - 1;
  const float* xr = x + (size_t)(b * TT + tp) * 4 * NN;
  for (int m = threadIdx.x; m < NN; m += 512) {
    float a = xr[m], e = xr[NN + m], c = xr[2 * NN + m];
    rx[m] = a; ry[m] = e; rz[m] = c;
    rr[m] = __fadd_rn(__fadd_rn(__fmul_rn(a, a), __fmul_rn(e, e)), __fmul_rn(c, c));
  }
  __syncthreads();
  int n = blockIdx.x * 512 + threadIdx.x;
  const float* xq = x + (size_t)(b * TT + t) * 4 * NN;
  float qx = xq[n], qy = xq[NN + n], qz = xq[2 * NN + n];
  float q2 = __fadd_rn(__fadd_rn(__fmul_rn(qx, qx), __fmul_rn(qy, qy)), __fmul_rn(qz, qz));
  float bd[KK]; int bi[KK];
#pragma unroll
  for (int i = 0; i < KK; ++i) { bd[i] = 3.402823466e38f; bi[i] = 0; }
  for (int m = 0; m < NN; ++m) {
    float s = __fmaf_rn(qz, rz[m], __fmaf_rn(qy, ry[m], __fmaf_rn(qx, rx[m], 0.0f)));
    float d2 = __fsub_rn(__fadd_rn(q2, rr[m]), __fmul_rn(2.0f, s));
    if (d2 < bd[KK - 1]) {
#pragma unroll
      for (int i = KK - 1; i > 0; --i) {
        float pv = bd[i - 1]; int pi = bi[i - 1];
        if (pv > d2)            { bd[i] = pv; bi[i] = pi; }
        else if (bd[i] > d2)    { bd[i] = d2; bi[i] = m; }
      }
      if (bd[0] > d2) { bd[0] = d2; bi[0] = m; }
    }
  }
  size_t base = ((size_t)(b * TT + t) * NN + n) * KK;
#pragma unroll
  for (int i = 0; i < KK; ++i) { gind[base + i] = bi[i]; gfloat[base + i] = (float)bi[i]; }
}

// ---------------------------------------------------------------------------
// R8-proven GEMM (prologue only, KA=4): A=Wa@pos_t+b, G=Wg@[pp;hTg].
// ---------------------------------------------------------------------------
template<int KA>
__global__ __launch_bounds__(256) void gemm_ag(
    const float* __restrict__ WgT, const float* __restrict__ WaT,
    const float* __restrict__ bias, const float* __restrict__ x,
    const float* __restrict__ hTg, size_t hTg_bstr,
    const float* __restrict__ hTa,
    int t, int tp,
    float* __restrict__ Aout, float* __restrict__ Gout)
{
  int tid = threadIdx.x;
  int w = tid >> 6, lane = tid & 63;
  int bid = blockIdx.x;
  int b = (bid >> 1) & 3;
  int sub = (bid >> 3) * 2 + (bid & 1);
  int ob = sub >> 4, nb = sub & 15;
  int o0u = __builtin_amdgcn_readfirstlane(ob * 16 + w * 4);
  int n = nb * 64 + lane;

  float aG[4] = {0.f, 0.f, 0.f, 0.f};
  float aA[4] = {0.f, 0.f, 0.f, 0.f};

  const float* xg = x + (size_t)(b * TT + tp) * 4 * NN + n;
  const float* xa = x + (size_t)(b * TT + t) * 4 * NN + n;

#pragma unroll
  for (int k = 0; k < 4; ++k) {
    const float* wg = WgT + (size_t)k * NO + o0u;
    const float* wa = WaT + (size_t)k * NO + o0u;
    float gv = xg[(size_t)k * NN];
    float av = xa[(size_t)k * NN];
#pragma unroll
    for (int i = 0; i < 4; ++i) {
      aG[i] = fmaf(wg[i], gv, aG[i]);
      aA[i] = fmaf(wa[i], av, aA[i]);
    }
  }

  const float* hg = hTg + (size_t)b * hTg_bstr + n;
  const float* ha = hTa + (size_t)b * H_BSTR + n;
#pragma unroll 4
  for (int k = 0; k < HDIM; ++k) {
    const float* wg = WgT + (size_t)(4 + k) * NO + o0u;
    float gv = hg[(size_t)k * NN];
#pragma unroll
    for (int i = 0; i < 4; ++i) aG[i] = fmaf(wg[i], gv, aG[i]);
    if (KA == 132) {
      const float* wa = WaT + (size_t)(4 + k) * NO + o0u;
      float av = ha[(size_t)k * NN];
#pragma unroll
      for (int i = 0; i < 4; ++i) aA[i] = fmaf(wa[i], av, aA[i]);
    }
  }

  const float* bv = bias + o0u;
  size_t row = ((size_t)b * NN + n) * NO + o0u;
  *(float4*)&Gout[row] = make_float4(aG[0], aG[1], aG[2], aG[3]);
  *(float4*)&Aout[row] = make_float4(aA[0] + bv[0], aA[1] + bv[1],
                                     aA[2] + bv[2], aA[3] + bv[3]);
}

// ---------------------------------------------------------------------------
// Fused 4-output GEMM (runs after each ew pair). Plain args.
//   G1_{t1+1} = Wg1 @ [pos_tg;  h1_{t1}]          (h1src: out slot t1 / zeros)
//   A1_{t1+1} = Wa1 @ [pos_t0;  h0_{t0}] + b1     (t0 = t1+1; h0 from h0T)
//   G0_{t0+1} = Wg0 @ [pos_t0;  h0_{t0}]          (shares loads with A1)
//   A0_{t0+1} = Wa0 @  pos_ta0            + b0    (ta0 = min(t0+1, 31))
// Mapping/fma-order identical to the proven R6 gemm_gg / R8 gemm_ag bodies.
// ---------------------------------------------------------------------------
__global__ __launch_bounds__(256) void gemm3(
    const float* __restrict__ WgT0, const float* __restrict__ WgT1,
    const float* __restrict__ WaT1, const float* __restrict__ WaT0,
    const float* __restrict__ b1v, const float* __restrict__ b0v,
    const float* __restrict__ x,
    const float* __restrict__ h1src, size_t h1bstr,
    const float* __restrict__ h0T,
    int tg, int t0, int ta0,
    float* __restrict__ G1out, float* __restrict__ A1out,
    float* __restrict__ G0out, float* __restrict__ A0out)
{
  int tid = threadIdx.x;
  int w = tid >> 6, lane = tid & 63;
  int bid = blockIdx.x;
  int b = (bid >> 1) & 3;
  int sub = (bid >> 3) * 2 + (bid & 1);
  int ob = sub >> 4, nb = sub & 15;
  int o0u = __builtin_amdgcn_readfirstlane(ob * 16 + w * 4);
  int n = nb * 64 + lane;

  float aG1[4] = {0.f, 0.f, 0.f, 0.f};
  float aA1[4] = {0.f, 0.f, 0.f, 0.f};
  float aG0[4] = {0.f, 0.f, 0.f, 0.f};
  float aA0[4] = {0.f, 0.f, 0.f, 0.f};

  const float* xg = x + (size_t)(b * TT + tg) * 4 * NN + n;   // pp for G1
  const float* xa = x + (size_t)(b * TT + t0) * 4 * NN + n;   // pos for A1/G0
  const float* x0 = x + (size_t)(b * TT + ta0) * 4 * NN + n;  // pos for A0

#pragma unroll
  for (int k = 0; k < 4; ++k) {
    const float* wg1 = WgT1 + (size_t)k * NO + o0u;
    const float* wa1 = WaT1 + (size_t)k * NO + o0u;
    const float* wg0 = WgT0 + (size_t)k * NO + o0u;
    const float* wa0 = WaT0 + (size_t)k * NO + o0u;
    float gv = xg[(size_t)k * NN];
    float av = xa[(size_t)k * NN];
    float a0v = x0[(size_t)k * NN];
#pragma unroll
    for (int i = 0; i < 4; ++i) {
      aG1[i] = fmaf(wg1[i], gv, aG1[i]);
      aA1[i] = fmaf(wa1[i], av, aA1[i]);
      aG0[i] = fmaf(wg0[i], av, aG0[i]);
      aA0[i] = fmaf(wa0[i], a0v, aA0[i]);
    }
  }

  const float* h1 = h1src + (size_t)b * h1bstr + n;
  const float* h0 = h0T + (size_t)b * H_BSTR + n;
#pragma unroll 4
  for (int k = 0; k < HDIM; ++k) {
    const float* wg1 = WgT1 + (size_t)(4 + k) * NO + o0u;
    const float* wa1 = WaT1 + (size_t)(4 + k) * NO + o0u;
    const float* wg0 = WgT0 + (size_t)(4 + k) * NO + o0u;
    float g1v = h1[(size_t)k * NN];
    float h0v = h0[(size_t)k * NN];
#pragma unroll
    for (int i = 0; i < 4; ++i) {
      aG1[i] = fmaf(wg1[i], g1v, aG1[i]);
      aA1[i] = fmaf(wa1[i], h0v, aA1[i]);
      aG0[i] = fmaf(wg0[i], h0v, aG0[i]);
    }
  }

  const float* bv1 = b1v + o0u;
  const float* bv0 = b0v + o0u;
  size_t row = ((size_t)b * NN + n) * NO + o0u;
  *(float4*)&G1out[row] = make_float4(aG1[0], aG1[1], aG1[2], aG1[3]);
  *(float4*)&A1out[row] = make_float4(aA1[0] + bv1[0], aA1[1] + bv1[1],
                                      aA1[2] + bv1[2], aA1[3] + bv1[3]);
  *(float4*)&G0out[row] = make_float4(aG0[0], aG0[1], aG0[2], aG0[3]);
  *(float4*)&A0out[row] = make_float4(aA0[0] + bv0[0], aA0[1] + bv0[1],
                                      aA0[2] + bv0[2], aA0[3] + bv0[3]);
}

// ---------------------------------------------------------------------------
// R8-proven ew body as a device function (byte-identical math/IO pattern).
// ---------------------------------------------------------------------------
__device__ __forceinline__ void ew_body(
    int b, int n, int nb8, int tid, int t,
    const float* __restrict__ A, const float* __restrict__ G,
    const int* __restrict__ gind,
    const float* __restrict__ c_in, float* __restrict__ c_out,
    float* __restrict__ hT, size_t hT_bstr,
    float (*htile)[9])
{
  int j = tid & 127, ns = tid >> 7;
  const float* Ap = A + ((size_t)b * NN + n) * NO;
  float a0 = Ap[j], a1 = Ap[128 + j], a2 = Ap[256 + j], a3 = Ap[384 + j];
  const int* ip = gind + ((size_t)(b * TT + t) * NN + n) * KK;
  const float* Gb = G + (size_t)b * NN * NO;
  const float* cb = c_in + (size_t)b * NN * HDIM;
  float hmax = -3.402823466e38f, cmax = -3.402823466e38f;
#pragma unroll 4
  for (int k = 0; k < KK; ++k) {
    int m = __builtin_amdgcn_readfirstlane(ip[k]);   // wave-uniform
    const float* Gp = Gb + (size_t)m * NO;
    float gi = a0 + Gp[j];
    float gf = a1 + Gp[128 + j];
    float go = a2 + Gp[256 + j];
    float gg = a3 + Gp[384 + j];
    float cg = cb[(size_t)m * HDIM + j];
    float si = 1.0f / (1.0f + __expf(-gi));
    float sf = 1.0f / (1.0f + __expf(-gf));
    float so = 1.0f / (1.0f + __expf(-go));
    float tg = 1.0f - 2.0f / (1.0f + __expf(2.0f * gg));
    float cn = sf * cg + si * tg;
    float tc = 1.0f - 2.0f / (1.0f + __expf(2.0f * cn));
    float hn = so * tc;
    hmax = fmaxf(hmax, hn);
    cmax = fmaxf(cmax, cn);
  }
  c_out[((size_t)b * NN + n) * HDIM + j] = cmax;
  htile[j][ns] = hmax;
  __syncthreads();
  int jw = tid >> 3, nn = tid & 7;
  hT[(size_t)b * hT_bstr + (size_t)jw * NN + nb8 * 8 + nn] = htile[jw][nn];
}

// R8-proven standalone ew (prologue ew0_0 / epilogue ew1_31). 512 blocks.
__global__ __launch_bounds__(1024) void ew_step(
    const float* __restrict__ A, const float* __restrict__ G,
    const int* __restrict__ gind,
    const float* __restrict__ c_in, float* __restrict__ c_out,
    float* __restrict__ hT, size_t hT_bstr, int t)
{
  __shared__ float htile[HDIM][9];
  int bid = blockIdx.x;
  int b = (bid >> 1) & 3;
  int nb8 = (bid >> 3) * 2 + (bid & 1);
  int tid = threadIdx.x;
  int n = nb8 * 8 + (tid >> 7);
  ew_body(b, n, nb8, tid, t, A, G, gind, c_in, c_out, hT, hT_bstr, htile);
}

// Fused double ew: 1024 blocks; role=bid&1 (block-uniform pointer mux, no
// early return, no divergent code before the barrier).
//   role 1: ew1_{t1}: A1,G1,c1 -> out slot t1
//   role 0: ew0_{t0}: A0,G0,c0 -> h0T          (t0 = t1+1)
__global__ __launch_bounds__(1024) void ew2(
    const float* __restrict__ A1, const float* __restrict__ G1,
    const float* __restrict__ A0, const float* __restrict__ G0,
    const int* __restrict__ gind,
    const float* __restrict__ c1in, float* __restrict__ c1out,
    const float* __restrict__ c0in, float* __restrict__ c0out,
    float* __restrict__ h1out, float* __restrict__ h0T,
    int t1, int t0)
{
  __shared__ float htile[HDIM][9];
  int bid = blockIdx.x;
  int role = bid & 1;
  int sub = bid >> 1;
  int b = (sub >> 1) & 3;
  int nb8 = (sub >> 3) * 2 + (sub & 1);
  int tid = threadIdx.x;
  int n = nb8 * 8 + (tid >> 7);

  const float* A   = role ? A1 : A0;
  const float* G   = role ? G1 : G0;
  const float* cin = role ? c1in : c0in;
  float* cout      = role ? c1out : c0out;
  float* hT        = role ? h1out : h0T;
  size_t hbstr     = role ? OUT_BSTR : H_BSTR;
  int t            = role ? t1 : t0;

  ew_body(b, n, nb8, tid, t, A, G, gind, cin, cout, hT, hbstr, htile);
}

// Transpose (b,n,j)[N][128] -> dst[dstBase + b*bStride + j*N + n]  (for c out)
__global__ __launch_bounds__(256) void transpose_nj_jn(
    const float* __restrict__ src, float* __restrict__ dst,
    size_t dstBase, size_t bStride)
{
  __shared__ float tl[64][65];
  int tid = threadIdx.x;
  int n0 = blockIdx.x * 64, j0 = blockIdx.y * 64, b = blockIdx.z;
  int c = tid & 63, r4 = tid >> 6;
#pragma unroll
  for (int i = 0; i < 16; ++i) {
    int r = r4 + i * 4;
    tl[r][c] = src[((size_t)b * NN + n0 + r) * HDIM + j0 + c];
  }
  __syncthreads();
  float* dp = dst + dstBase + (size_t)b * bStride;
#pragma unroll
  for (int i = 0; i < 16; ++i) {
    int rr = r4 + i * 4;
    dp[(size_t)(j0 + rr) * NN + n0 + c] = tl[c][rr];
  }
}

// h output = copy of out1 slot at t=T-1 (already j-major)
__global__ __launch_bounds__(256) void copy_h(const float* __restrict__ out1,
                                              float* __restrict__ dst)
{
  int i = blockIdx.x * 256 + threadIdx.x;
  if (i >= BB * HDIM * NN) return;
  int b = i / (HDIM * NN);
  int r = i - b * (HDIM * NN);
  dst[i] = out1[((size_t)(b * TT + TT - 1) * 132 + 4) * NN + r];
}

// out1 position channels
__global__ __launch_bounds__(256) void pos_copy(const float* __restrict__ x,
                                                float* __restrict__ out)
{
  int i = blockIdx.x * 256 + threadIdx.x;
  if (i >= BB * TT * 4 * NN) return;
  int n = i & (NN - 1);
  int btc = i >> 10;
  int c = btc & 3, bt = btc >> 2;
  out[((size_t)bt * 132 + c) * NN + n] = x[i];
}

extern "C" void kernel_launch(void* const* d_in, const int* in_sizes, int n_in,
                              void* d_out, int out_size, void* d_ws, size_t ws_size,
                              hipStream_t stream)
{
  const float* x  = (const float*)d_in[0];
  const float* w0 = (const float*)d_in[1];
  const float* b0 = (const float*)d_in[2];
  const float* w1 = (const float*)d_in[3];
  const float* b1 = (const float*)d_in[4];
  float* out = (float*)d_out;

  float* wsf = (float*)d_ws;
  int*   gind = (int*)d_ws;
  size_t off = (size_t)BB * TT * NN * KK;          // gind ints
  const size_t HSZ = (size_t)BB * NN * HDIM;       // 524288
  float* h0T = wsf + off; off += HSZ;
  float* c0a = wsf + off; off += HSZ;
  float* c0b = wsf + off; off += HSZ;
  float* c1a = wsf + off; off += HSZ;
  float* c1b = wsf + off; off += HSZ;
  float* zeros = wsf + off; off += (size_t)HDIM * NN;
  float* A1buf = wsf + off; off += (size_t)BB * NN * NO;
  float* G1buf = wsf + off; off += (size_t)BB * NN * NO;
  float* A0buf = wsf + off; off += (size_t)BB * NN * NO;
  float* G0buf = wsf + off; off += (size_t)BB * NN * NO;
  float* WaT0 = wsf + off; off += 4 * NO;
  float* WgT0 = wsf + off; off += (size_t)KG * NO;
  float* WaT1 = wsf + off; off += (size_t)KG * NO;
  float* WgT1 = wsf + off; off += (size_t)KG * NO;

  hipMemsetAsync(c0a, 0, HSZ * 4, stream);
  hipMemsetAsync(c1a, 0, HSZ * 4, stream);
  hipMemsetAsync(zeros, 0, (size_t)HDIM * NN * 4, stream);

  prep_weights<<<(KG * NO + 255) / 256, 256, 0, stream>>>(w0, w1, WaT0, WgT0, WaT1, WgT1);
  knn_kernel<<<dim3(2, TT, BB), 512, 0, stream>>>(x, gind, out + OG);
  pos_copy<<<(BB * TT * 4 * NN + 255) / 256, 256, 0, stream>>>(x, out);

  float* c0[2] = {c0a, c0b};
  float* c1[2] = {c1a, c1b};

  // ---- prologue: A0_0/G0_0 (proven gemm_ag<4>, hTg=zeros), ew0_0, then
  //      gemm3 -> G1_0 (h1=0), A1_0, G0_1, A0_1.
  gemm_ag<4><<<dim3(2048), 256, 0, stream>>>(
      WgT0, WaT0, b0, x, zeros, 0, h0T, /*t=*/0, /*tp=*/0, A0buf, G0buf);
  ew_step<<<dim3(512), 1024, 0, stream>>>(
      A0buf, G0buf, gind, c0a, c0b, h0T, H_BSTR, 0);
  gemm3<<<dim3(2048), 256, 0, stream>>>(
      WgT0, WgT1, WaT1, WaT0, b1, b0, x,
      zeros, 0, h0T, /*tg=*/0, /*t0=*/0, /*ta0=*/1,
      G1buf, A1buf, G0buf, A0buf);

  // ---- main loop: t1 = 0..30
  for (int t1 = 0; t1 < TT - 1; ++t1) {
    int t0 = t1 + 1;
    ew2<<<dim3(1024), 1024, 0, stream>>>(
        A1buf, G1buf, A0buf, G0buf, gind,
        c1[t1 & 1], c1[(t1 & 1) ^ 1],
        c0[t0 & 1], c0[(t0 & 1) ^ 1],
        out + ((size_t)t1 * 132 + 4) * NN, h0T, t1, t0);
    int ta0 = (t0 + 1 < TT) ? t0 + 1 : TT - 1;
    gemm3<<<dim3(2048), 256, 0, stream>>>(
        WgT0, WgT1, WaT1, WaT0, b1, b0, x,
        out + ((size_t)t1 * 132 + 4) * NN, OUT_BSTR, h0T,
        /*tg=*/t1, /*t0=*/t0, ta0,
        G1buf, A1buf, G0buf, A0buf);
  }

  // ---- epilogue: ew1_31 (proven ew_step); c1 in = c1[31&1]=c1b, out = c1a
  ew_step<<<dim3(512), 1024, 0, stream>>>(
      A1buf, G1buf, gind, c1b, c1a,
      out + ((size_t)(TT - 1) * 132 + 4) * NN, OUT_BSTR, TT - 1);

  // final h (copy of last out1 slot) and c (ew1_31 wrote c1a)
  copy_h<<<(BB * HDIM * NN + 255) / 256, 256, 0, stream>>>(out, out + OH);
  transpose_nj_jn<<<dim3(16, 2, BB), 256, 0, stream>>>(c1a, out, OC, (size_t)HDIM * NN);
}